// Round 11
// baseline (823.160 us; speedup 1.0000x reference)
//
#include <hip/hip_runtime.h>

#define N_NODES 10000
#define E_EDGES 320000
#define ND 256
#define ED 128

// ---- workspace layout (BYTE offsets); total ~26.3 MB ----
#define B_AM   0          // bf16 [10000][256]
#define B_BM   5120000    // bf16 [10000][256]
#define B_AE   10240000   // bf16 [10000][128]
#define B_BE   12800000   // bf16 [10000][128]
#define B_P1   15360000   // f32 [10000]
#define B_P2   15400960   // f32 [10000]
#define B_XA   15441920   // f32 [10000][256] accumulator
#define B_DEN  25681920   // f32 [10000]
#define B_CNT  25722880   // int [10000]
#define B_ROW  25763840   // int [10000]
#define B_CUR  25804800   // int [10000]
#define B_EID  25845760   // int [320000] CSR edge ids
#define B_WT   27125760   // bf16 weight tables, 425984 bytes

// weight tables, PACKED per 4 col-groups in wave-read order:
// [wc(4)][kk(NK)][cf(CF)][lane(64)][j(8)] bf16 -> 1KB coalesced blocks
#define M0T 0
#define M1T 65536
#define M2T 196608
#define E0T 327680
#define E1T 360448
#define E2T 393216

// ---- LDS: four 16KB panels [64 rows][256B] + control ----
#define R0 0
#define R1 16384
#define R2 32768
#define R3 49152
#define AL_S  65536
#define SRC_S 65792
#define DST_S 66048
#define EID_S 66304
#define LDS_TOT 66560

#define BM 64
#define NTILES (E_EDGES / BM)   // 5000, divisible by 8 -> exact XCD swizzle

typedef float  float4v __attribute__((ext_vector_type(4)));
typedef short  short8  __attribute__((ext_vector_type(8)));

__device__ __forceinline__ unsigned short f2bf(float f) {
    unsigned int b = __float_as_uint(f);
    return (unsigned short)((b + 0x7FFFu + ((b >> 16) & 1u)) >> 16);
}
__device__ __forceinline__ float bf2f(unsigned short u) {
    return __uint_as_float(((unsigned int)u) << 16);
}
#define PK2(a,b) ((unsigned int)(a) | ((unsigned int)(b) << 16))

// Non-draining barrier: waits only LDS ops (producer ds_writes visible), then
// raw s_barrier. Unlike __syncthreads(), does NOT emit s_waitcnt vmcnt(0) —
// global B-prefetch loads stay in flight across phase boundaries (T4).
__device__ __forceinline__ void bar_ldsonly() {
    asm volatile("s_waitcnt lgkmcnt(0)" ::: "memory");
    __builtin_amdgcn_s_barrier();
}

// ---------------- init ----------------
__global__ void k_init(float* xa, float* den, int* cnt, int* cur) {
    int i = blockIdx.x * blockDim.x + threadIdx.x;
    int st = gridDim.x * blockDim.x;
    for (int j = i; j < N_NODES * ND; j += st) xa[j] = 0.f;
    for (int j = i; j < N_NODES; j += st) { den[j] = 0.f; cnt[j] = 0; cur[j] = 0; }
}

// ---------------- CSR build ----------------
__global__ void k_deg(const int* ei, int* cnt) {
    int e = blockIdx.x * 256 + threadIdx.x;
    if (e < E_EDGES) atomicAdd(&cnt[ei[e]], 1);
}

__global__ void k_scan(const int* cnt, int* rowstart) {
    __shared__ int part[256];
    int t = threadIdx.x;
    int base = t * 40;
    int s = 0;
    for (int i = 0; i < 40; i++) { int idx = base + i; if (idx < N_NODES) s += cnt[idx]; }
    part[t] = s;
    __syncthreads();
    if (t == 0) { int run = 0; for (int i = 0; i < 256; i++) { int v = part[i]; part[i] = run; run += v; } }
    __syncthreads();
    int run = part[t];
    for (int i = 0; i < 40; i++) {
        int idx = base + i;
        if (idx < N_NODES) { rowstart[idx] = run; run += cnt[idx]; }
    }
}

__global__ void k_fill(const int* ei, const int* rowstart, int* cur, int* eidcsr) {
    int e = blockIdx.x * 256 + threadIdx.x;
    if (e >= E_EDGES) return;
    int s = ei[e];
    int p = atomicAdd(&cur[s], 1);
    eidcsr[rowstart[s] + p] = e;
}

// ---------------- weight convert, PACKED 4-group ----------------
__global__ void k_wconv(const float* mw0, const float* mw1, const float* mw2,
                        const float* ew0, const float* ew1, const float* ew2, char* wtb) {
    const int tot = 212992;
    for (int idx = blockIdx.x * blockDim.x + threadIdx.x; idx < tot;
         idx += gridDim.x * blockDim.x) {
        int local, K, N, base; const float* src;
        if (idx < 32768)       { local = idx;          K = 128; N = 256; src = mw0 + 512*256; base = M0T; }
        else if (idx < 98304)  { local = idx - 32768;  K = 256; N = 256; src = mw1;           base = M1T; }
        else if (idx < 163840) { local = idx - 98304;  K = 256; N = 256; src = mw2;           base = M2T; }
        else if (idx < 180224) { local = idx - 163840; K = 128; N = 128; src = ew0 + 512*128; base = E0T; }
        else if (idx < 196608) { local = idx - 180224; K = 128; N = 128; src = ew1;           base = E1T; }
        else                   { local = idx - 196608; K = 128; N = 128; src = ew2;           base = E2T; }
        int W4 = N / 4;
        int CF = W4 >> 4;
        int NK = K / 32;
        int t = local;
        int j    = t & 7;   t >>= 3;
        int lane = t & 63;  t >>= 6;
        int cf   = t % CF;  t /= CF;
        int kk   = t % NK;  t /= NK;
        int wc   = t;
        int col = wc * W4 + cf * 16 + (lane & 15);
        int k   = kk * 32 + (lane >> 4) * 8 + j;
        ((unsigned short*)(wtb + base))[local] = f2bf(src[k * N + col]);
    }
}

// ---------------- node precompute ----------------
__global__ __launch_bounds__(256) void k_nodepre(
    const float* na, const float* mw0, const float* ew0, const float* aw,
    const float* mb0, const float* eb0, const float* ab, char* wsb) {
    __shared__ float at[256 * 32];
    int tid = threadIdx.x;
    int r0 = blockIdx.x * 32;
    int nr = N_NODES - r0; if (nr > 32) nr = 32;
    {
        int r = tid & 31, kq = tid >> 5;
        if (r < nr) {
            const float* src = na + (size_t)(r0 + r) * ND + kq * 32;
            for (int i = 0; i < 32; i += 4) {
                float4 v = *(const float4*)(src + i);
                at[(kq*32 + i + 0)*32 + r] = v.x;
                at[(kq*32 + i + 1)*32 + r] = v.y;
                at[(kq*32 + i + 2)*32 + r] = v.z;
                at[(kq*32 + i + 3)*32 + r] = v.w;
            }
        } else {
            for (int i = 0; i < 32; i++) at[(kq*32 + i)*32 + r] = 0.f;
        }
    }
    __syncthreads();
    int c = blockIdx.y * 256 + tid;
    if (c >= 770) return;
    const float* wp; int wstep; float bias;
    unsigned short* opu = nullptr; float* opf = nullptr; int ostride;
    if (c < 256)      { wp = mw0 + c;                 wstep = 256; bias = mb0[c];     opu = (unsigned short*)(wsb + B_AM) + c;       ostride = 256; }
    else if (c < 512) { wp = mw0 + 65536 + (c - 256); wstep = 256; bias = 0.f;        opu = (unsigned short*)(wsb + B_BM) + (c-256); ostride = 256; }
    else if (c < 640) { wp = ew0 + (c - 512);         wstep = 128; bias = eb0[c-512]; opu = (unsigned short*)(wsb + B_AE) + (c-512); ostride = 128; }
    else if (c < 768) { wp = ew0 + 32768 + (c - 640); wstep = 128; bias = 0.f;        opu = (unsigned short*)(wsb + B_BE) + (c-640); ostride = 128; }
    else if (c == 768){ wp = aw;                      wstep = 1;   bias = ab[0];      opf = (float*)(wsb + B_P1);                    ostride = 1; }
    else              { wp = aw + 256;                wstep = 1;   bias = 0.f;        opf = (float*)(wsb + B_P2);                    ostride = 1; }
    float acc[32];
    #pragma unroll
    for (int r = 0; r < 32; r++) acc[r] = 0.f;
    for (int k = 0; k < 256; k++) {
        float w = wp[k * wstep];
        const float* a = &at[k * 32];
        #pragma unroll
        for (int r4 = 0; r4 < 8; r4++) {
            float4 a4 = *(const float4*)(a + r4 * 4);
            acc[r4*4+0] += a4.x * w; acc[r4*4+1] += a4.y * w;
            acc[r4*4+2] += a4.z * w; acc[r4*4+3] += a4.w * w;
        }
    }
    if (opu) { for (int r = 0; r < nr; r++) opu[(size_t)(r0 + r) * ostride] = f2bf(acc[r] + bias); }
    else     { for (int r = 0; r < nr; r++) opf[(size_t)(r0 + r)] = acc[r] + bias; }
}

// ---------------- fused per-edge MLP main kernel ----------------
struct DP {
    const float* ea; const int* ei; const int* csr;
    const unsigned short* Am; const unsigned short* Bm;
    const unsigned short* Ae; const unsigned short* Be;
    const float* p1; const float* p2; const float* aw;
    const float* mb1; const float* mb2; const float* eb1; const float* eb2;
    const char* wtb;
    float* xa; float* den; float* eout;
};

__device__ __forceinline__ int pan_addr(int blo, int bhi, int row, int col) {
    int base = (col & 128) ? bhi : blo;
    return base + row * 256 + ((((col & 127)) * 2) ^ ((row & 7) << 4));
}
__device__ __forceinline__ int dump_addr(int row, int col) {
    return row * 1024 + (((col * 4)) ^ ((row & 15) << 6));
}

// EPI: 0=m0(Am/Bm gather+relu->h) 1=bias+relu->h 2=m2(mb2,*ex,fp32 dump)
//      3=e0(Ae/Be gather+relu->h) 4=e2(eb2 -> eout scatter by eid)
template<int KTOT, int NOUT, int EPI, int NXT_N>
__device__ __forceinline__ void do_gemm(char* sm, const DP& p,
                                        int a_lo, int a_hi, const char* wt,
                                        int h_lo, int h_hi, const float* bias,
                                        const char* wt_next, short8 (&bbuf)[2][4],
                                        int wr, int wc, int lane) {
    constexpr int WCOL = NOUT / 4;
    constexpr int CF   = WCOL / 16;              // 4 or 2
    constexpr int NK   = KTOT / 32;
    constexpr int KH   = NK * CF / 4;            // even
    constexpr int NKH  = NK / KH;
    const int l15 = lane & 15, lg = lane >> 4;
    const float4v vz = {0.f, 0.f, 0.f, 0.f};
    float4v acc[2][CF];
    #pragma unroll
    for (int i = 0; i < 2; i++)
        #pragma unroll
        for (int j = 0; j < CF; j++) acc[i][j] = vz;
    bar_ldsonly();   // LDS producer/consumer sync; B-loads stay in flight
    short8 areg[2][2];
    #pragma unroll
    for (int rf = 0; rf < 2; rf++)
        areg[0][rf] = *(const short8*)(sm + pan_addr(a_lo, a_hi, wr*32 + rf*16 + l15, lg*8));
    #pragma unroll
    for (int h = 0; h < KH; h++) {
        if (h + 1 < KH) {
            #pragma unroll
            for (int i = 0; i < 4; i++)
                bbuf[(h+1)&1][i] = *(const short8*)(wt + ((size_t)((h+1)*4 + i) * 64 + lane) * 16);
        } else if constexpr (NXT_N > 0) {
            #pragma unroll
            for (int i = 0; i < NXT_N; i++)
                bbuf[(h+1)&1][i] = *(const short8*)(wt_next + ((size_t)i * 64 + lane) * 16);
        }
        #pragma unroll
        for (int ks = 0; ks < NKH; ks++) {
            int kstep = h * NKH + ks;
            if (kstep + 1 < NK) {
                int ke = (kstep + 1) * 32 + lg * 8;
                #pragma unroll
                for (int rf = 0; rf < 2; rf++)
                    areg[(kstep+1)&1][rf] = *(const short8*)(sm + pan_addr(a_lo, a_hi, wr*32 + rf*16 + l15, ke));
            }
            __builtin_amdgcn_s_setprio(1);
            #pragma unroll
            for (int rf = 0; rf < 2; rf++)
                #pragma unroll
                for (int cf = 0; cf < CF; cf++)
                    acc[rf][cf] = __builtin_amdgcn_mfma_f32_16x16x32_bf16(areg[kstep&1][rf], bbuf[h&1][ks*CF+cf], acc[rf][cf], 0, 0, 0);
            __builtin_amdgcn_s_setprio(0);
        }
    }
    if constexpr (EPI == 2) bar_ldsonly();   // dump overwrites A panels
    const int*   srcid = (const int*)(sm + SRC_S);
    const int*   dstid = (const int*)(sm + DST_S);
    const int*   eid   = (const int*)(sm + EID_S);
    const float* exv   = (const float*)(sm + AL_S);
    #pragma unroll
    for (int rf = 0; rf < 2; rf++)
        #pragma unroll
        for (int cf = 0; cf < CF; cf++)
            #pragma unroll
            for (int j = 0; j < 4; j++) {
                int row = wr * 32 + rf * 16 + lg * 4 + j;
                int col = wc * WCOL + cf * 16 + l15;
                float v = acc[rf][cf][j];
                if constexpr (EPI == 0) {
                    v += bf2f(p.Am[(size_t)srcid[row] * ND + col]) + bf2f(p.Bm[(size_t)dstid[row] * ND + col]);
                    v = fmaxf(v, 0.f);
                    *(unsigned short*)(sm + pan_addr(h_lo, h_hi, row, col)) = f2bf(v);
                } else if constexpr (EPI == 1) {
                    v += bias[col]; v = fmaxf(v, 0.f);
                    *(unsigned short*)(sm + pan_addr(h_lo, h_hi, row, col)) = f2bf(v);
                } else if constexpr (EPI == 2) {
                    v = (v + p.mb2[col]) * exv[row];
                    *(float*)(sm + dump_addr(row, col)) = v;
                } else if constexpr (EPI == 3) {
                    v += bf2f(p.Ae[(size_t)srcid[row] * ED + col]) + bf2f(p.Be[(size_t)dstid[row] * ED + col]);
                    v = fmaxf(v, 0.f);
                    *(unsigned short*)(sm + pan_addr(h_lo, h_hi, row, col)) = f2bf(v);
                } else {
                    v += p.eb2[col];
                    p.eout[(size_t)eid[row] * ED + col] = v;
                }
            }
}

__global__ __launch_bounds__(512, 4) void k_main(DP p) {
    extern __shared__ char sm[];
    const int tid = threadIdx.x;
    const int lane = tid & 63, wv = tid >> 6;
    const int wr = wv >> 2, wc = wv & 3;
    // XCD-bijective swizzle (NTILES % 8 == 0): each XCD gets a contiguous
    // tile range -> weight tables + sorted-src xa/atomics local to one L2.
    const int tile = (blockIdx.x & 7) * (NTILES / 8) + (blockIdx.x >> 3);
    const int s0 = tile * BM;

    const char* wtE0 = p.wtb + E0T + (size_t)wc * 8192;
    const char* wtE1 = p.wtb + E1T + (size_t)wc * 8192;
    const char* wtE2 = p.wtb + E2T + (size_t)wc * 8192;
    const char* wtM0 = p.wtb + M0T + (size_t)wc * 16384;
    const char* wtM1 = p.wtb + M1T + (size_t)wc * 32768;
    const char* wtM2 = p.wtb + M2T + (size_t)wc * 32768;

    short8 bbuf[2][4];
    #pragma unroll
    for (int i = 0; i < 4; i++)
        bbuf[0][i] = *(const short8*)(wtE0 + ((size_t)i * 64 + lane) * 16);

    if (tid < BM) {
        int eid = p.csr[s0 + tid];
        ((int*)(sm + EID_S))[tid] = eid;
        ((int*)(sm + SRC_S))[tid] = p.ei[eid];
        ((int*)(sm + DST_S))[tid] = p.ei[E_EDGES + eid];
    }
    // stage: gather edge_attr row, pack bf16 swizzled into R0, fused att+exp
    {
        int r = tid >> 3, cq = tid & 7;
        int eid = p.csr[s0 + r];
        const float4* src = (const float4*)(p.ea + (size_t)eid * ED + cq * 16);
        const float4* wvp = (const float4*)(p.aw + 512 + cq * 16);
        int s = (r & 7) << 4;
        float4 v0 = src[0], v1 = src[1], v2 = src[2], v3 = src[3];
        float4 w0 = wvp[0], w1 = wvp[1], w2 = wvp[2], w3 = wvp[3];
        float sd = v0.x*w0.x + v0.y*w0.y + v0.z*w0.z + v0.w*w0.w
                 + v1.x*w1.x + v1.y*w1.y + v1.z*w1.z + v1.w*w1.w
                 + v2.x*w2.x + v2.y*w2.y + v2.z*w2.z + v2.w*w2.w
                 + v3.x*w3.x + v3.y*w3.y + v3.z*w3.z + v3.w*w3.w;
        unsigned short u[16] = {f2bf(v0.x),f2bf(v0.y),f2bf(v0.z),f2bf(v0.w),
                                f2bf(v1.x),f2bf(v1.y),f2bf(v1.z),f2bf(v1.w),
                                f2bf(v2.x),f2bf(v2.y),f2bf(v2.z),f2bf(v2.w),
                                f2bf(v3.x),f2bf(v3.y),f2bf(v3.z),f2bf(v3.w)};
        int cb = cq * 32;
        *(uint4*)(sm + R0 + r*256 + (cb ^ s)) =
            make_uint4(PK2(u[0],u[1]), PK2(u[2],u[3]), PK2(u[4],u[5]), PK2(u[6],u[7]));
        *(uint4*)(sm + R0 + r*256 + ((cb + 16) ^ s)) =
            make_uint4(PK2(u[8],u[9]), PK2(u[10],u[11]), PK2(u[12],u[13]), PK2(u[14],u[15]));
        sd += __shfl_xor(sd, 1); sd += __shfl_xor(sd, 2); sd += __shfl_xor(sd, 4);
        if (cq == 0) {
            int sn = p.ei[eid];
            int dn = p.ei[E_EDGES + eid];
            float a = sd + p.p1[sn] + p.p2[dn];
            float ex = __expf(a);                 // max-free: att bounded ~|6|
            ((float*)(sm + AL_S))[r] = ex;
            unsafeAtomicAdd(&p.den[sn], ex);
        }
    }
    // e-chain (ea in R0 live through m0)
    do_gemm<128,128,3,4>(sm, p, R0, 0,  wtE0, R1, 0,  nullptr, wtE1, bbuf, wr, wc, lane);
    do_gemm<128,128,1,4>(sm, p, R1, 0,  wtE1, R2, 0,  p.eb1,   wtE2, bbuf, wr, wc, lane);
    do_gemm<128,128,4,4>(sm, p, R2, 0,  wtE2, 0,  0,  nullptr, wtM0, bbuf, wr, wc, lane);
    // m-chain: h0m -> (R1,R2), h1m -> (R0,R3), m2 dumps fp32 to R0..R3
    do_gemm<128,256,0,4>(sm, p, R0, 0,  wtM0, R1, R2, nullptr, wtM1, bbuf, wr, wc, lane);
    do_gemm<256,256,1,4>(sm, p, R1, R2, wtM1, R0, R3, p.mb1,   wtM2, bbuf, wr, wc, lane);
    do_gemm<256,256,2,0>(sm, p, R0, R3, wtM2, 0,  0,  nullptr, nullptr, bbuf, wr, wc, lane);
    bar_ldsonly();
    // segmented reduction over sorted src: one atomic per (segment, col)
    {
        const int* srcid = (const int*)(sm + SRC_S);
        int h = tid >> 8;
        int c = tid & 255;
        int rend = h * 32 + 31;
        float acc = 0.f;
        for (int r = h * 32; r <= rend; r++) {
            acc += *(const float*)(sm + dump_addr(r, c));
            if (r == rend || srcid[r + 1] != srcid[r]) {
                unsafeAtomicAdd(&p.xa[(size_t)srcid[r] * ND + c], acc);
                acc = 0.f;
            }
        }
    }
}

// ---------------- normalize ----------------
__global__ void k_norm(const float* xa, const float* den, float* xout) {
    int i = blockIdx.x * 256 + threadIdx.x;
    if (i >= N_NODES * ND) return;
    float d = den[i >> 8];
    xout[i] = (d > 0.f) ? xa[i] / d : 0.f;
}

extern "C" void kernel_launch(void* const* d_in, const int* in_sizes, int n_in,
                              void* d_out, int out_size, void* d_ws, size_t ws_size,
                              hipStream_t stream) {
    const float* na  = (const float*)d_in[0];
    const float* ea  = (const float*)d_in[1];
    const int*   ei  = (const int*)d_in[2];
    const float* mw0 = (const float*)d_in[3];
    const float* mb0 = (const float*)d_in[4];
    const float* mw1 = (const float*)d_in[5];
    const float* mb1 = (const float*)d_in[6];
    const float* mw2 = (const float*)d_in[7];
    const float* mb2 = (const float*)d_in[8];
    const float* ew0 = (const float*)d_in[9];
    const float* eb0 = (const float*)d_in[10];
    const float* ew1 = (const float*)d_in[11];
    const float* eb1 = (const float*)d_in[12];
    const float* ew2 = (const float*)d_in[13];
    const float* eb2 = (const float*)d_in[14];
    const float* aw  = (const float*)d_in[15];
    const float* ab  = (const float*)d_in[16];
    float* out = (float*)d_out;
    char*  wsb = (char*)d_ws;

    float* xout = out;
    float* eout = out + (size_t)N_NODES * ND;

    float* xa  = (float*)(wsb + B_XA);
    float* den = (float*)(wsb + B_DEN);
    int*   cnt = (int*)(wsb + B_CNT);
    int*   row = (int*)(wsb + B_ROW);
    int*   cur = (int*)(wsb + B_CUR);
    int*   eidcsr = (int*)(wsb + B_EID);

    k_init<<<512, 256, 0, stream>>>(xa, den, cnt, cur);
    k_deg<<<1250, 256, 0, stream>>>(ei, cnt);
    k_scan<<<1, 256, 0, stream>>>(cnt, row);
    k_fill<<<1250, 256, 0, stream>>>(ei, row, cur, eidcsr);
    k_wconv<<<256, 256, 0, stream>>>(mw0, mw1, mw2, ew0, ew1, ew2, wsb + B_WT);
    k_nodepre<<<dim3(313, 4), 256, 0, stream>>>(na, mw0, ew0, aw, mb0, eb0, ab, wsb);

    DP p{ea, ei, eidcsr,
         (const unsigned short*)(wsb + B_AM), (const unsigned short*)(wsb + B_BM),
         (const unsigned short*)(wsb + B_AE), (const unsigned short*)(wsb + B_BE),
         (const float*)(wsb + B_P1), (const float*)(wsb + B_P2), aw,
         mb1, mb2, eb1, eb2, (const char*)(wsb + B_WT), xa, den, eout};
    hipFuncSetAttribute((const void*)k_main, hipFuncAttributeMaxDynamicSharedMemorySize, LDS_TOT);
    k_main<<<NTILES, 512, LDS_TOT, stream>>>(p);
    k_norm<<<10000, 256, 0, stream>>>(xa, den, xout);
}

// Round 12
// 592.492 us; speedup vs baseline: 1.3893x; 1.3893x over previous
//
#include <hip/hip_runtime.h>

#define N_NODES 10000
#define E_EDGES 320000
#define ND 256
#define ED 128

// ---- workspace layout (BYTE offsets); total ~26.3 MB ----
#define B_AM   0          // bf16 [10000][256]
#define B_BM   5120000    // bf16 [10000][256]
#define B_AE   10240000   // bf16 [10000][128]
#define B_BE   12800000   // bf16 [10000][128]
#define B_P1   15360000   // f32 [10000]
#define B_P2   15400960   // f32 [10000]
#define B_XA   15441920   // f32 [10000][256] accumulator
#define B_DEN  25681920   // f32 [10000]
#define B_CNT  25722880   // int [10000]
#define B_ROW  25763840   // int [10000]
#define B_CUR  25804800   // int [10000]
#define B_EID  25845760   // int [320000] CSR edge ids
#define B_WT   27125760   // bf16 weight tables, 425984 bytes

// weight tables, PACKED per 4 col-groups in wave-read order:
// [wc(4)][kk(NK)][cf(CF)][lane(64)][j(8)] bf16 -> 1KB coalesced blocks
#define M0T 0
#define M1T 65536
#define M2T 196608
#define E0T 327680
#define E1T 360448
#define E2T 393216

// ---- LDS: four 16KB panels [64 rows][256B] + control ----
#define R0 0
#define R1 16384
#define R2 32768
#define R3 49152
#define AL_S  65536
#define SRC_S 65792
#define DST_S 66048
#define EID_S 66304
#define LDS_TOT 66560

#define BM 64
#define NTILES (E_EDGES / BM)

typedef float  float4v __attribute__((ext_vector_type(4)));
typedef short  short8  __attribute__((ext_vector_type(8)));

__device__ __forceinline__ unsigned short f2bf(float f) {
    unsigned int b = __float_as_uint(f);
    return (unsigned short)((b + 0x7FFFu + ((b >> 16) & 1u)) >> 16);
}
__device__ __forceinline__ float bf2f(unsigned short u) {
    return __uint_as_float(((unsigned int)u) << 16);
}
#define PK2(a,b) ((unsigned int)(a) | ((unsigned int)(b) << 16))

// Non-draining barrier (T4): waits LDS ops only, then raw s_barrier.
// __syncthreads() would emit s_waitcnt vmcnt(0) and drain the in-flight
// global B-prefetches at EVERY phase boundary (8x/tile), restarting the
// load pipeline cold. All LDS producer->consumer ordering is lgkmcnt-counted,
// so this is sufficient for panel correctness; global loads are consumed
// only via compiler-inserted vmcnt waits at first use.
__device__ __forceinline__ void bar_ldsonly() {
    asm volatile("s_waitcnt lgkmcnt(0)" ::: "memory");
    __builtin_amdgcn_s_barrier();
}

// ---------------- init ----------------
__global__ void k_init(float* xa, float* den, int* cnt, int* cur) {
    int i = blockIdx.x * blockDim.x + threadIdx.x;
    int st = gridDim.x * blockDim.x;
    for (int j = i; j < N_NODES * ND; j += st) xa[j] = 0.f;
    for (int j = i; j < N_NODES; j += st) { den[j] = 0.f; cnt[j] = 0; cur[j] = 0; }
}

// ---------------- CSR build ----------------
__global__ void k_deg(const int* ei, int* cnt) {
    int e = blockIdx.x * 256 + threadIdx.x;
    if (e < E_EDGES) atomicAdd(&cnt[ei[e]], 1);
}

// parallel scan: 1 block x 1024 threads, wave shuffle-scan (was serial in t0)
__global__ __launch_bounds__(1024) void k_scan(const int* cnt, int* rowstart) {
    __shared__ int wsum[16];
    int t = threadIdx.x, lane = t & 63, w = t >> 6;
    int base = t * 10;                      // 1024*10 >= 10000
    int loc[10];
    int s = 0;
    #pragma unroll
    for (int i = 0; i < 10; i++) {
        int idx = base + i;
        int v = (idx < N_NODES) ? cnt[idx] : 0;
        loc[i] = s; s += v;
    }
    int run = s;                            // inclusive scan across wave
    #pragma unroll
    for (int d = 1; d < 64; d <<= 1) {
        int u = __shfl_up(run, d);
        if (lane >= d) run += u;
    }
    if (lane == 63) wsum[w] = run;
    __syncthreads();
    if (w == 0 && lane < 16) {
        int v = wsum[lane];
        int r = v;
        #pragma unroll
        for (int d = 1; d < 16; d <<= 1) {
            int u = __shfl_up(r, d);
            if (lane >= d) r += u;
        }
        wsum[lane] = r - v;                 // exclusive
    }
    __syncthreads();
    int ex = wsum[w] + run - s;             // exclusive prefix for this thread
    #pragma unroll
    for (int i = 0; i < 10; i++) {
        int idx = base + i;
        if (idx < N_NODES) rowstart[idx] = ex + loc[i];
    }
}

__global__ void k_fill(const int* ei, const int* rowstart, int* cur, int* eidcsr) {
    int e = blockIdx.x * 256 + threadIdx.x;
    if (e >= E_EDGES) return;
    int s = ei[e];
    int p = atomicAdd(&cur[s], 1);
    eidcsr[rowstart[s] + p] = e;
}

// ---------------- weight convert, PACKED 4-group ----------------
__global__ void k_wconv(const float* mw0, const float* mw1, const float* mw2,
                        const float* ew0, const float* ew1, const float* ew2, char* wtb) {
    const int tot = 212992;
    for (int idx = blockIdx.x * blockDim.x + threadIdx.x; idx < tot;
         idx += gridDim.x * blockDim.x) {
        int local, K, N, base; const float* src;
        if (idx < 32768)       { local = idx;          K = 128; N = 256; src = mw0 + 512*256; base = M0T; }
        else if (idx < 98304)  { local = idx - 32768;  K = 256; N = 256; src = mw1;           base = M1T; }
        else if (idx < 163840) { local = idx - 98304;  K = 256; N = 256; src = mw2;           base = M2T; }
        else if (idx < 180224) { local = idx - 163840; K = 128; N = 128; src = ew0 + 512*128; base = E0T; }
        else if (idx < 196608) { local = idx - 180224; K = 128; N = 128; src = ew1;           base = E1T; }
        else                   { local = idx - 196608; K = 128; N = 128; src = ew2;           base = E2T; }
        int W4 = N / 4;
        int CF = W4 >> 4;
        int NK = K / 32;
        int t = local;
        int j    = t & 7;   t >>= 3;
        int lane = t & 63;  t >>= 6;
        int cf   = t % CF;  t /= CF;
        int kk   = t % NK;  t /= NK;
        int wc   = t;
        int col = wc * W4 + cf * 16 + (lane & 15);
        int k   = kk * 32 + (lane >> 4) * 8 + j;
        ((unsigned short*)(wtb + base))[local] = f2bf(src[k * N + col]);
    }
}

// ---------------- node precompute ----------------
__global__ __launch_bounds__(256) void k_nodepre(
    const float* na, const float* mw0, const float* ew0, const float* aw,
    const float* mb0, const float* eb0, const float* ab, char* wsb) {
    __shared__ float at[256 * 32];
    int tid = threadIdx.x;
    int r0 = blockIdx.x * 32;
    int nr = N_NODES - r0; if (nr > 32) nr = 32;
    {
        int r = tid & 31, kq = tid >> 5;
        if (r < nr) {
            const float* src = na + (size_t)(r0 + r) * ND + kq * 32;
            for (int i = 0; i < 32; i += 4) {
                float4 v = *(const float4*)(src + i);
                at[(kq*32 + i + 0)*32 + r] = v.x;
                at[(kq*32 + i + 1)*32 + r] = v.y;
                at[(kq*32 + i + 2)*32 + r] = v.z;
                at[(kq*32 + i + 3)*32 + r] = v.w;
            }
        } else {
            for (int i = 0; i < 32; i++) at[(kq*32 + i)*32 + r] = 0.f;
        }
    }
    __syncthreads();
    int c = blockIdx.y * 256 + tid;
    if (c >= 770) return;
    const float* wp; int wstep; float bias;
    unsigned short* opu = nullptr; float* opf = nullptr; int ostride;
    if (c < 256)      { wp = mw0 + c;                 wstep = 256; bias = mb0[c];     opu = (unsigned short*)(wsb + B_AM) + c;       ostride = 256; }
    else if (c < 512) { wp = mw0 + 65536 + (c - 256); wstep = 256; bias = 0.f;        opu = (unsigned short*)(wsb + B_BM) + (c-256); ostride = 256; }
    else if (c < 640) { wp = ew0 + (c - 512);         wstep = 128; bias = eb0[c-512]; opu = (unsigned short*)(wsb + B_AE) + (c-512); ostride = 128; }
    else if (c < 768) { wp = ew0 + 32768 + (c - 640); wstep = 128; bias = 0.f;        opu = (unsigned short*)(wsb + B_BE) + (c-640); ostride = 128; }
    else if (c == 768){ wp = aw;                      wstep = 1;   bias = ab[0];      opf = (float*)(wsb + B_P1);                    ostride = 1; }
    else              { wp = aw + 256;                wstep = 1;   bias = 0.f;        opf = (float*)(wsb + B_P2);                    ostride = 1; }
    float acc[32];
    #pragma unroll
    for (int r = 0; r < 32; r++) acc[r] = 0.f;
    for (int k = 0; k < 256; k++) {
        float w = wp[k * wstep];
        const float* a = &at[k * 32];
        #pragma unroll
        for (int r4 = 0; r4 < 8; r4++) {
            float4 a4 = *(const float4*)(a + r4 * 4);
            acc[r4*4+0] += a4.x * w; acc[r4*4+1] += a4.y * w;
            acc[r4*4+2] += a4.z * w; acc[r4*4+3] += a4.w * w;
        }
    }
    if (opu) { for (int r = 0; r < nr; r++) opu[(size_t)(r0 + r) * ostride] = f2bf(acc[r] + bias); }
    else     { for (int r = 0; r < nr; r++) opf[(size_t)(r0 + r)] = acc[r] + bias; }
}

// ---------------- fused per-edge MLP main kernel ----------------
struct DP {
    const float* ea; const int* ei; const int* csr;
    const unsigned short* Am; const unsigned short* Bm;
    const unsigned short* Ae; const unsigned short* Be;
    const float* p1; const float* p2; const float* aw;
    const float* mb1; const float* mb2; const float* eb1; const float* eb2;
    const char* wtb;
    float* xa; float* den; float* eout;
};

__device__ __forceinline__ int pan_addr(int blo, int bhi, int row, int col) {
    int base = (col & 128) ? bhi : blo;
    return base + row * 256 + ((((col & 127)) * 2) ^ ((row & 7) << 4));
}
__device__ __forceinline__ int dump_addr(int row, int col) {
    return row * 1024 + (((col * 4)) ^ ((row & 15) << 6));
}

// EPI: 0=m0(Am/Bm gather+relu->h) 1=bias+relu->h 2=m2(mb2,*ex,fp32 dump)
//      3=e0(Ae/Be gather+relu->h) 4=e2(eb2 -> eout scatter by eid)
template<int KTOT, int NOUT, int EPI, int NXT_N>
__device__ __forceinline__ void do_gemm(char* sm, const DP& p,
                                        int a_lo, int a_hi, const char* wt,
                                        int h_lo, int h_hi, const float* bias,
                                        const char* wt_next, short8 (&bbuf)[2][4],
                                        int wr, int wc, int lane) {
    constexpr int WCOL = NOUT / 4;
    constexpr int CF   = WCOL / 16;              // 4 or 2
    constexpr int NK   = KTOT / 32;
    constexpr int KH   = NK * CF / 4;            // even
    constexpr int NKH  = NK / KH;
    const int l15 = lane & 15, lg = lane >> 4;
    const float4v vz = {0.f, 0.f, 0.f, 0.f};
    float4v acc[2][CF];
    #pragma unroll
    for (int i = 0; i < 2; i++)
        #pragma unroll
        for (int j = 0; j < CF; j++) acc[i][j] = vz;
    bar_ldsonly();   // LDS sync only; B-prefetch loads stay in flight (T4)
    short8 areg[2][2];
    #pragma unroll
    for (int rf = 0; rf < 2; rf++)
        areg[0][rf] = *(const short8*)(sm + pan_addr(a_lo, a_hi, wr*32 + rf*16 + l15, lg*8));
    #pragma unroll
    for (int h = 0; h < KH; h++) {
        if (h + 1 < KH) {
            #pragma unroll
            for (int i = 0; i < 4; i++)
                bbuf[(h+1)&1][i] = *(const short8*)(wt + ((size_t)((h+1)*4 + i) * 64 + lane) * 16);
        } else if constexpr (NXT_N > 0) {
            #pragma unroll
            for (int i = 0; i < NXT_N; i++)
                bbuf[(h+1)&1][i] = *(const short8*)(wt_next + ((size_t)i * 64 + lane) * 16);
        }
        #pragma unroll
        for (int ks = 0; ks < NKH; ks++) {
            int kstep = h * NKH + ks;
            if (kstep + 1 < NK) {
                int ke = (kstep + 1) * 32 + lg * 8;
                #pragma unroll
                for (int rf = 0; rf < 2; rf++)
                    areg[(kstep+1)&1][rf] = *(const short8*)(sm + pan_addr(a_lo, a_hi, wr*32 + rf*16 + l15, ke));
            }
            #pragma unroll
            for (int rf = 0; rf < 2; rf++)
                #pragma unroll
                for (int cf = 0; cf < CF; cf++)
                    acc[rf][cf] = __builtin_amdgcn_mfma_f32_16x16x32_bf16(areg[kstep&1][rf], bbuf[h&1][ks*CF+cf], acc[rf][cf], 0, 0, 0);
        }
    }
    if constexpr (EPI == 2) bar_ldsonly();   // dump overwrites A panels
    const int*   srcid = (const int*)(sm + SRC_S);
    const int*   dstid = (const int*)(sm + DST_S);
    const int*   eid   = (const int*)(sm + EID_S);
    const float* exv   = (const float*)(sm + AL_S);
    #pragma unroll
    for (int rf = 0; rf < 2; rf++)
        #pragma unroll
        for (int cf = 0; cf < CF; cf++)
            #pragma unroll
            for (int j = 0; j < 4; j++) {
                int row = wr * 32 + rf * 16 + lg * 4 + j;
                int col = wc * WCOL + cf * 16 + l15;
                float v = acc[rf][cf][j];
                if constexpr (EPI == 0) {
                    v += bf2f(p.Am[(size_t)srcid[row] * ND + col]) + bf2f(p.Bm[(size_t)dstid[row] * ND + col]);
                    v = fmaxf(v, 0.f);
                    *(unsigned short*)(sm + pan_addr(h_lo, h_hi, row, col)) = f2bf(v);
                } else if constexpr (EPI == 1) {
                    v += bias[col]; v = fmaxf(v, 0.f);
                    *(unsigned short*)(sm + pan_addr(h_lo, h_hi, row, col)) = f2bf(v);
                } else if constexpr (EPI == 2) {
                    v = (v + p.mb2[col]) * exv[row];
                    *(float*)(sm + dump_addr(row, col)) = v;
                } else if constexpr (EPI == 3) {
                    v += bf2f(p.Ae[(size_t)srcid[row] * ED + col]) + bf2f(p.Be[(size_t)dstid[row] * ED + col]);
                    v = fmaxf(v, 0.f);
                    *(unsigned short*)(sm + pan_addr(h_lo, h_hi, row, col)) = f2bf(v);
                } else {
                    v += p.eb2[col];
                    p.eout[(size_t)eid[row] * ED + col] = v;
                }
            }
}

__global__ __launch_bounds__(512, 4) void k_main(DP p) {
    extern __shared__ char sm[];
    const int tid = threadIdx.x;
    const int lane = tid & 63, wv = tid >> 6;
    const int wr = wv >> 2, wc = wv & 3;
    const int s0 = blockIdx.x * BM;      // natural order (no XCD swizzle — r11 errata)

    const char* wtE0 = p.wtb + E0T + (size_t)wc * 8192;
    const char* wtE1 = p.wtb + E1T + (size_t)wc * 8192;
    const char* wtE2 = p.wtb + E2T + (size_t)wc * 8192;
    const char* wtM0 = p.wtb + M0T + (size_t)wc * 16384;
    const char* wtM1 = p.wtb + M1T + (size_t)wc * 32768;
    const char* wtM2 = p.wtb + M2T + (size_t)wc * 32768;

    short8 bbuf[2][4];
    #pragma unroll
    for (int i = 0; i < 4; i++)
        bbuf[0][i] = *(const short8*)(wtE0 + ((size_t)i * 64 + lane) * 16);

    if (tid < BM) {
        int eid = p.csr[s0 + tid];
        ((int*)(sm + EID_S))[tid] = eid;
        ((int*)(sm + SRC_S))[tid] = p.ei[eid];
        ((int*)(sm + DST_S))[tid] = p.ei[E_EDGES + eid];
    }
    // stage: gather edge_attr row, pack bf16 swizzled into R0, fused att+exp
    {
        int r = tid >> 3, cq = tid & 7;
        int eid = p.csr[s0 + r];
        const float4* src = (const float4*)(p.ea + (size_t)eid * ED + cq * 16);
        const float4* wvp = (const float4*)(p.aw + 512 + cq * 16);
        int s = (r & 7) << 4;
        float4 v0 = src[0], v1 = src[1], v2 = src[2], v3 = src[3];
        float4 w0 = wvp[0], w1 = wvp[1], w2 = wvp[2], w3 = wvp[3];
        float sd = v0.x*w0.x + v0.y*w0.y + v0.z*w0.z + v0.w*w0.w
                 + v1.x*w1.x + v1.y*w1.y + v1.z*w1.z + v1.w*w1.w
                 + v2.x*w2.x + v2.y*w2.y + v2.z*w2.z + v2.w*w2.w
                 + v3.x*w3.x + v3.y*w3.y + v3.z*w3.z + v3.w*w3.w;
        unsigned short u[16] = {f2bf(v0.x),f2bf(v0.y),f2bf(v0.z),f2bf(v0.w),
                                f2bf(v1.x),f2bf(v1.y),f2bf(v1.z),f2bf(v1.w),
                                f2bf(v2.x),f2bf(v2.y),f2bf(v2.z),f2bf(v2.w),
                                f2bf(v3.x),f2bf(v3.y),f2bf(v3.z),f2bf(v3.w)};
        int cb = cq * 32;
        *(uint4*)(sm + R0 + r*256 + (cb ^ s)) =
            make_uint4(PK2(u[0],u[1]), PK2(u[2],u[3]), PK2(u[4],u[5]), PK2(u[6],u[7]));
        *(uint4*)(sm + R0 + r*256 + ((cb + 16) ^ s)) =
            make_uint4(PK2(u[8],u[9]), PK2(u[10],u[11]), PK2(u[12],u[13]), PK2(u[14],u[15]));
        sd += __shfl_xor(sd, 1); sd += __shfl_xor(sd, 2); sd += __shfl_xor(sd, 4);
        if (cq == 0) {
            int sn = p.ei[eid];
            int dn = p.ei[E_EDGES + eid];
            float a = sd + p.p1[sn] + p.p2[dn];
            float ex = __expf(a);                 // max-free: att bounded ~|6|
            ((float*)(sm + AL_S))[r] = ex;
            unsafeAtomicAdd(&p.den[sn], ex);
        }
    }
    // e-chain (ea in R0 live through m0)
    do_gemm<128,128,3,4>(sm, p, R0, 0,  wtE0, R1, 0,  nullptr, wtE1, bbuf, wr, wc, lane);
    do_gemm<128,128,1,4>(sm, p, R1, 0,  wtE1, R2, 0,  p.eb1,   wtE2, bbuf, wr, wc, lane);
    do_gemm<128,128,4,4>(sm, p, R2, 0,  wtE2, 0,  0,  nullptr, wtM0, bbuf, wr, wc, lane);
    // m-chain: h0m -> (R1,R2), h1m -> (R0,R3), m2 dumps fp32 to R0..R3
    do_gemm<128,256,0,4>(sm, p, R0, 0,  wtM0, R1, R2, nullptr, wtM1, bbuf, wr, wc, lane);
    do_gemm<256,256,1,4>(sm, p, R1, R2, wtM1, R0, R3, p.mb1,   wtM2, bbuf, wr, wc, lane);
    do_gemm<256,256,2,0>(sm, p, R0, R3, wtM2, 0,  0,  nullptr, nullptr, bbuf, wr, wc, lane);
    bar_ldsonly();
    // segmented reduction over sorted src: one atomic per (segment, col)
    {
        const int* srcid = (const int*)(sm + SRC_S);
        int h = tid >> 8;
        int c = tid & 255;
        int rend = h * 32 + 31;
        float acc = 0.f;
        for (int r = h * 32; r <= rend; r++) {
            acc += *(const float*)(sm + dump_addr(r, c));
            if (r == rend || srcid[r + 1] != srcid[r]) {
                unsafeAtomicAdd(&p.xa[(size_t)srcid[r] * ND + c], acc);
                acc = 0.f;
            }
        }
    }
}

// ---------------- normalize ----------------
__global__ void k_norm(const float* xa, const float* den, float* xout) {
    int i = blockIdx.x * 256 + threadIdx.x;
    if (i >= N_NODES * ND) return;
    float d = den[i >> 8];
    xout[i] = (d > 0.f) ? xa[i] / d : 0.f;
}

extern "C" void kernel_launch(void* const* d_in, const int* in_sizes, int n_in,
                              void* d_out, int out_size, void* d_ws, size_t ws_size,
                              hipStream_t stream) {
    const float* na  = (const float*)d_in[0];
    const float* ea  = (const float*)d_in[1];
    const int*   ei  = (const int*)d_in[2];
    const float* mw0 = (const float*)d_in[3];
    const float* mb0 = (const float*)d_in[4];
    const float* mw1 = (const float*)d_in[5];
    const float* mb1 = (const float*)d_in[6];
    const float* mw2 = (const float*)d_in[7];
    const float* mb2 = (const float*)d_in[8];
    const float* ew0 = (const float*)d_in[9];
    const float* eb0 = (const float*)d_in[10];
    const float* ew1 = (const float*)d_in[11];
    const float* eb1 = (const float*)d_in[12];
    const float* ew2 = (const float*)d_in[13];
    const float* eb2 = (const float*)d_in[14];
    const float* aw  = (const float*)d_in[15];
    const float* ab  = (const float*)d_in[16];
    float* out = (float*)d_out;
    char*  wsb = (char*)d_ws;

    float* xout = out;
    float* eout = out + (size_t)N_NODES * ND;

    float* xa  = (float*)(wsb + B_XA);
    float* den = (float*)(wsb + B_DEN);
    int*   cnt = (int*)(wsb + B_CNT);
    int*   row = (int*)(wsb + B_ROW);
    int*   cur = (int*)(wsb + B_CUR);
    int*   eidcsr = (int*)(wsb + B_EID);

    k_init<<<512, 256, 0, stream>>>(xa, den, cnt, cur);
    k_deg<<<1250, 256, 0, stream>>>(ei, cnt);
    k_scan<<<1, 1024, 0, stream>>>(cnt, row);
    k_fill<<<1250, 256, 0, stream>>>(ei, row, cur, eidcsr);
    k_wconv<<<256, 256, 0, stream>>>(mw0, mw1, mw2, ew0, ew1, ew2, wsb + B_WT);
    k_nodepre<<<dim3(313, 4), 256, 0, stream>>>(na, mw0, ew0, aw, mb0, eb0, ab, wsb);

    DP p{ea, ei, eidcsr,
         (const unsigned short*)(wsb + B_AM), (const unsigned short*)(wsb + B_BM),
         (const unsigned short*)(wsb + B_AE), (const unsigned short*)(wsb + B_BE),
         (const float*)(wsb + B_P1), (const float*)(wsb + B_P2), aw,
         mb1, mb2, eb1, eb2, (const char*)(wsb + B_WT), xa, den, eout};
    hipFuncSetAttribute((const void*)k_main, hipFuncAttributeMaxDynamicSharedMemorySize, LDS_TOT);
    k_main<<<NTILES, 512, LDS_TOT, stream>>>(p);
    k_norm<<<10000, 256, 0, stream>>>(xa, den, xout);
}

// Round 13
// 503.506 us; speedup vs baseline: 1.6349x; 1.1767x over previous
//
#include <hip/hip_runtime.h>
#include <hip/hip_bf16.h>

#define N_NODES 10000
#define E_EDGES 320000
#define ND 256
#define ED 128

// ---- workspace layout (BYTE offsets); total ~26.3 MB ----
#define B_AM   0          // bf16 [10000][256]
#define B_BM   5120000    // bf16 [10000][256]
#define B_AE   10240000   // bf16 [10000][128]
#define B_BE   12800000   // bf16 [10000][128]
#define B_P1   15360000   // f32 [10000]
#define B_P2   15400960   // f32 [10000]
#define B_XA   15441920   // f32 [10000][256] accumulator
#define B_DEN  25681920   // f32 [10000]
#define B_CNT  25722880   // int [10000]
#define B_ROW  25763840   // int [10000]
#define B_CUR  25804800   // int [10000]
#define B_EID  25845760   // int [320000] CSR edge ids
#define B_WT   27125760   // bf16 weight tables, 425984 bytes

// weight tables, PACKED per 4 col-groups in wave-read order:
// [wc(4)][kk(NK)][cf(CF)][lane(64)][j(8)] bf16 -> 1KB coalesced blocks
#define M0T 0
#define M1T 65536
#define M2T 196608
#define E0T 327680
#define E1T 360448
#define E2T 393216

// ---- LDS: four 16KB panels [64 rows][256B] + control ----
#define R0 0
#define R1 16384
#define R2 32768
#define R3 49152
#define AL_S  65536
#define SRC_S 65792
#define DST_S 66048
#define EID_S 66304
#define LDS_TOT 66560

#define BM 64
#define NTILES (E_EDGES / BM)

typedef float  float4v __attribute__((ext_vector_type(4)));
typedef short  short8  __attribute__((ext_vector_type(8)));

__device__ __forceinline__ unsigned short f2bf(float f) {
    unsigned int b = __float_as_uint(f);
    return (unsigned short)((b + 0x7FFFu + ((b >> 16) & 1u)) >> 16);
}
__device__ __forceinline__ float bf2f(unsigned short u) {
    return __uint_as_float(((unsigned int)u) << 16);
}
// HW-packed bf16 pair (v_cvt_pk_bf16_f32, RNE — bit-identical to f2bf pair).
__device__ __forceinline__ unsigned int pkbf(float a, float b) {
    __hip_bfloat162 h = __float22bfloat162_rn(float2{a, b});
    return *(unsigned int*)&h;
}

// Non-draining barrier (T4): waits LDS ops only, then raw s_barrier.
__device__ __forceinline__ void bar_ldsonly() {
    asm volatile("s_waitcnt lgkmcnt(0)" ::: "memory");
    __builtin_amdgcn_s_barrier();
}

// ---------------- init ----------------
__global__ void k_init(float* xa, float* den, int* cnt, int* cur) {
    int i = blockIdx.x * blockDim.x + threadIdx.x;
    int st = gridDim.x * blockDim.x;
    for (int j = i; j < N_NODES * ND; j += st) xa[j] = 0.f;
    for (int j = i; j < N_NODES; j += st) { den[j] = 0.f; cnt[j] = 0; cur[j] = 0; }
}

// ---------------- CSR build ----------------
__global__ void k_deg(const int* ei, int* cnt) {
    int e = blockIdx.x * 256 + threadIdx.x;
    if (e < E_EDGES) atomicAdd(&cnt[ei[e]], 1);
}

// parallel scan: 1 block x 1024 threads, wave shuffle-scan
__global__ __launch_bounds__(1024) void k_scan(const int* cnt, int* rowstart) {
    __shared__ int wsum[16];
    int t = threadIdx.x, lane = t & 63, w = t >> 6;
    int base = t * 10;
    int loc[10];
    int s = 0;
    #pragma unroll
    for (int i = 0; i < 10; i++) {
        int idx = base + i;
        int v = (idx < N_NODES) ? cnt[idx] : 0;
        loc[i] = s; s += v;
    }
    int run = s;
    #pragma unroll
    for (int d = 1; d < 64; d <<= 1) {
        int u = __shfl_up(run, d);
        if (lane >= d) run += u;
    }
    if (lane == 63) wsum[w] = run;
    __syncthreads();
    if (w == 0 && lane < 16) {
        int v = wsum[lane];
        int r = v;
        #pragma unroll
        for (int d = 1; d < 16; d <<= 1) {
            int u = __shfl_up(r, d);
            if (lane >= d) r += u;
        }
        wsum[lane] = r - v;
    }
    __syncthreads();
    int ex = wsum[w] + run - s;
    #pragma unroll
    for (int i = 0; i < 10; i++) {
        int idx = base + i;
        if (idx < N_NODES) rowstart[idx] = ex + loc[i];
    }
}

__global__ void k_fill(const int* ei, const int* rowstart, int* cur, int* eidcsr) {
    int e = blockIdx.x * 256 + threadIdx.x;
    if (e >= E_EDGES) return;
    int s = ei[e];
    int p = atomicAdd(&cur[s], 1);
    eidcsr[rowstart[s] + p] = e;
}

// ---------------- weight convert, PACKED 4-group ----------------
__global__ void k_wconv(const float* mw0, const float* mw1, const float* mw2,
                        const float* ew0, const float* ew1, const float* ew2, char* wtb) {
    const int tot = 212992;
    for (int idx = blockIdx.x * blockDim.x + threadIdx.x; idx < tot;
         idx += gridDim.x * blockDim.x) {
        int local, K, N, base; const float* src;
        if (idx < 32768)       { local = idx;          K = 128; N = 256; src = mw0 + 512*256; base = M0T; }
        else if (idx < 98304)  { local = idx - 32768;  K = 256; N = 256; src = mw1;           base = M1T; }
        else if (idx < 163840) { local = idx - 98304;  K = 256; N = 256; src = mw2;           base = M2T; }
        else if (idx < 180224) { local = idx - 163840; K = 128; N = 128; src = ew0 + 512*128; base = E0T; }
        else if (idx < 196608) { local = idx - 180224; K = 128; N = 128; src = ew1;           base = E1T; }
        else                   { local = idx - 196608; K = 128; N = 128; src = ew2;           base = E2T; }
        int W4 = N / 4;
        int CF = W4 >> 4;
        int NK = K / 32;
        int t = local;
        int j    = t & 7;   t >>= 3;
        int lane = t & 63;  t >>= 6;
        int cf   = t % CF;  t /= CF;
        int kk   = t % NK;  t /= NK;
        int wc   = t;
        int col = wc * W4 + cf * 16 + (lane & 15);
        int k   = kk * 32 + (lane >> 4) * 8 + j;
        ((unsigned short*)(wtb + base))[local] = f2bf(src[k * N + col]);
    }
}

// ---------------- node precompute: 8 rows/block, 2 ds_read per k ----------------
__global__ __launch_bounds__(256) void k_nodepre(
    const float* na, const float* mw0, const float* ew0, const float* aw,
    const float* mb0, const float* eb0, const float* ab, char* wsb) {
    __shared__ float at[256 * 8];     // [k][r], 8KB
    int tid = threadIdx.x;
    int r0 = blockIdx.x * 8;          // grid.x = 1250, exact coverage
    {
        int r = tid & 7, kq = tid >> 3;   // kq 0..31, 8 k's each
        const float* src = na + (size_t)(r0 + r) * ND + kq * 8;
        float4 v0 = *(const float4*)(src);
        float4 v1 = *(const float4*)(src + 4);
        int kb = kq * 8;
        at[(kb+0)*8 + r] = v0.x; at[(kb+1)*8 + r] = v0.y;
        at[(kb+2)*8 + r] = v0.z; at[(kb+3)*8 + r] = v0.w;
        at[(kb+4)*8 + r] = v1.x; at[(kb+5)*8 + r] = v1.y;
        at[(kb+6)*8 + r] = v1.z; at[(kb+7)*8 + r] = v1.w;
    }
    __syncthreads();
    int c = blockIdx.y * 256 + tid;
    if (c >= 770) return;
    const float* wp; int wstep; float bias;
    unsigned short* opu = nullptr; float* opf = nullptr; int ostride;
    if (c < 256)      { wp = mw0 + c;                 wstep = 256; bias = mb0[c];     opu = (unsigned short*)(wsb + B_AM) + c;       ostride = 256; }
    else if (c < 512) { wp = mw0 + 65536 + (c - 256); wstep = 256; bias = 0.f;        opu = (unsigned short*)(wsb + B_BM) + (c-256); ostride = 256; }
    else if (c < 640) { wp = ew0 + (c - 512);         wstep = 128; bias = eb0[c-512]; opu = (unsigned short*)(wsb + B_AE) + (c-512); ostride = 128; }
    else if (c < 768) { wp = ew0 + 32768 + (c - 640); wstep = 128; bias = 0.f;        opu = (unsigned short*)(wsb + B_BE) + (c-640); ostride = 128; }
    else if (c == 768){ wp = aw;                      wstep = 1;   bias = ab[0];      opf = (float*)(wsb + B_P1);                    ostride = 1; }
    else              { wp = aw + 256;                wstep = 1;   bias = 0.f;        opf = (float*)(wsb + B_P2);                    ostride = 1; }
    float acc[8];
    #pragma unroll
    for (int r = 0; r < 8; r++) acc[r] = 0.f;
    for (int k = 0; k < 256; k++) {
        float w = wp[k * wstep];
        const float* a = &at[k * 8];
        float4 a0 = *(const float4*)(a);
        float4 a1 = *(const float4*)(a + 4);
        acc[0] += a0.x * w; acc[1] += a0.y * w; acc[2] += a0.z * w; acc[3] += a0.w * w;
        acc[4] += a1.x * w; acc[5] += a1.y * w; acc[6] += a1.z * w; acc[7] += a1.w * w;
    }
    if (opu) { for (int r = 0; r < 8; r++) opu[(size_t)(r0 + r) * ostride] = f2bf(acc[r] + bias); }
    else     { for (int r = 0; r < 8; r++) opf[(size_t)(r0 + r)] = acc[r] + bias; }
}

// ---------------- fused per-edge MLP main kernel ----------------
struct DP {
    const float* ea; const int* ei; const int* csr;
    const unsigned short* Am; const unsigned short* Bm;
    const unsigned short* Ae; const unsigned short* Be;
    const float* p1; const float* p2; const float* aw;
    const float* mb1; const float* mb2; const float* eb1; const float* eb2;
    const char* wtb;
    float* xa; float* den; float* eout;
};

__device__ __forceinline__ int pan_addr(int blo, int bhi, int row, int col) {
    int base = (col & 128) ? bhi : blo;
    return base + row * 256 + ((((col & 127)) * 2) ^ ((row & 7) << 4));
}
__device__ __forceinline__ int dump_addr(int row, int col) {
    return row * 1024 + (((col * 4)) ^ ((row & 15) << 6));
}

// EPI: 0=m0(Am/Bm gather+relu->h) 1=bias+relu->h 2=m2(mb2,*ex,fp32 dump)
//      3=e0(Ae/Be gather+relu->h) 4=e2(eb2 -> eout scatter by eid)
template<int KTOT, int NOUT, int EPI, int NXT_N>
__device__ __forceinline__ void do_gemm(char* sm, const DP& p,
                                        int a_lo, int a_hi, const char* wt,
                                        int h_lo, int h_hi, const float* bias,
                                        const char* wt_next, short8 (&bbuf)[2][4],
                                        int wr, int wc, int lane) {
    constexpr int WCOL = NOUT / 4;
    constexpr int CF   = WCOL / 16;              // 4 or 2
    constexpr int NK   = KTOT / 32;
    constexpr int KH   = NK * CF / 4;            // even
    constexpr int NKH  = NK / KH;
    const int l15 = lane & 15, lg = lane >> 4;
    const float4v vz = {0.f, 0.f, 0.f, 0.f};
    float4v acc[2][CF];
    #pragma unroll
    for (int i = 0; i < 2; i++)
        #pragma unroll
        for (int j = 0; j < CF; j++) acc[i][j] = vz;
    bar_ldsonly();   // LDS sync only; B-prefetch loads stay in flight (T4)
    short8 areg[2][2];
    #pragma unroll
    for (int rf = 0; rf < 2; rf++)
        areg[0][rf] = *(const short8*)(sm + pan_addr(a_lo, a_hi, wr*32 + rf*16 + l15, lg*8));
    #pragma unroll
    for (int h = 0; h < KH; h++) {
        if (h + 1 < KH) {
            #pragma unroll
            for (int i = 0; i < 4; i++)
                bbuf[(h+1)&1][i] = *(const short8*)(wt + ((size_t)((h+1)*4 + i) * 64 + lane) * 16);
        } else if constexpr (NXT_N > 0) {
            #pragma unroll
            for (int i = 0; i < NXT_N; i++)
                bbuf[(h+1)&1][i] = *(const short8*)(wt_next + ((size_t)i * 64 + lane) * 16);
        }
        #pragma unroll
        for (int ks = 0; ks < NKH; ks++) {
            int kstep = h * NKH + ks;
            if (kstep + 1 < NK) {
                int ke = (kstep + 1) * 32 + lg * 8;
                #pragma unroll
                for (int rf = 0; rf < 2; rf++)
                    areg[(kstep+1)&1][rf] = *(const short8*)(sm + pan_addr(a_lo, a_hi, wr*32 + rf*16 + l15, ke));
            }
            #pragma unroll
            for (int rf = 0; rf < 2; rf++)
                #pragma unroll
                for (int cf = 0; cf < CF; cf++)
                    acc[rf][cf] = __builtin_amdgcn_mfma_f32_16x16x32_bf16(areg[kstep&1][rf], bbuf[h&1][ks*CF+cf], acc[rf][cf], 0, 0, 0);
        }
    }
    if constexpr (EPI == 2) bar_ldsonly();   // dump overwrites A panels
    const int*   srcid = (const int*)(sm + SRC_S);
    const int*   dstid = (const int*)(sm + DST_S);
    const int*   eid   = (const int*)(sm + EID_S);
    const float* exv   = (const float*)(sm + AL_S);
    #pragma unroll
    for (int rf = 0; rf < 2; rf++)
        #pragma unroll
        for (int cf = 0; cf < CF; cf++) {
            int col = wc * WCOL + cf * 16 + l15;
            int row0 = wr * 32 + rf * 16 + lg * 4;
            if constexpr (EPI == 0 || EPI == 1 || EPI == 3) {
                float vv[4];
                #pragma unroll
                for (int j = 0; j < 4; j++) {
                    int row = row0 + j;
                    float v = acc[rf][cf][j];
                    if constexpr (EPI == 0)
                        v += bf2f(p.Am[(size_t)srcid[row] * ND + col]) + bf2f(p.Bm[(size_t)dstid[row] * ND + col]);
                    else if constexpr (EPI == 1)
                        v += bias[col];
                    else
                        v += bf2f(p.Ae[(size_t)srcid[row] * ED + col]) + bf2f(p.Be[(size_t)dstid[row] * ED + col]);
                    vv[j] = fmaxf(v, 0.f);
                }
                unsigned w01 = pkbf(vv[0], vv[1]);
                unsigned w23 = pkbf(vv[2], vv[3]);
                *(unsigned short*)(sm + pan_addr(h_lo, h_hi, row0 + 0, col)) = (unsigned short)w01;
                *(unsigned short*)(sm + pan_addr(h_lo, h_hi, row0 + 1, col)) = (unsigned short)(w01 >> 16);
                *(unsigned short*)(sm + pan_addr(h_lo, h_hi, row0 + 2, col)) = (unsigned short)w23;
                *(unsigned short*)(sm + pan_addr(h_lo, h_hi, row0 + 3, col)) = (unsigned short)(w23 >> 16);
            } else {
                #pragma unroll
                for (int j = 0; j < 4; j++) {
                    int row = row0 + j;
                    float v = acc[rf][cf][j];
                    if constexpr (EPI == 2) {
                        v = (v + p.mb2[col]) * exv[row];
                        *(float*)(sm + dump_addr(row, col)) = v;
                    } else {
                        v += p.eb2[col];
                        p.eout[(size_t)eid[row] * ED + col] = v;
                    }
                }
            }
        }
}

__global__ __launch_bounds__(512, 4) void k_main(DP p) {
    extern __shared__ char sm[];
    const int tid = threadIdx.x;
    const int lane = tid & 63, wv = tid >> 6;
    const int wr = wv >> 2, wc = wv & 3;
    const int s0 = blockIdx.x * BM;

    const char* wtE0 = p.wtb + E0T + (size_t)wc * 8192;
    const char* wtE1 = p.wtb + E1T + (size_t)wc * 8192;
    const char* wtE2 = p.wtb + E2T + (size_t)wc * 8192;
    const char* wtM0 = p.wtb + M0T + (size_t)wc * 16384;
    const char* wtM1 = p.wtb + M1T + (size_t)wc * 32768;
    const char* wtM2 = p.wtb + M2T + (size_t)wc * 32768;

    short8 bbuf[2][4];
    #pragma unroll
    for (int i = 0; i < 4; i++)
        bbuf[0][i] = *(const short8*)(wtE0 + ((size_t)i * 64 + lane) * 16);

    if (tid < BM) {
        int eid = p.csr[s0 + tid];
        ((int*)(sm + EID_S))[tid] = eid;
        ((int*)(sm + SRC_S))[tid] = p.ei[eid];
        ((int*)(sm + DST_S))[tid] = p.ei[E_EDGES + eid];
    }
    // stage: gather edge_attr row, pack bf16 (hw cvt_pk) swizzled into R0, fused att+exp
    {
        int r = tid >> 3, cq = tid & 7;
        int eid = p.csr[s0 + r];
        const float4* src = (const float4*)(p.ea + (size_t)eid * ED + cq * 16);
        const float4* wvp = (const float4*)(p.aw + 512 + cq * 16);
        int s = (r & 7) << 4;
        float4 v0 = src[0], v1 = src[1], v2 = src[2], v3 = src[3];
        float4 w0 = wvp[0], w1 = wvp[1], w2 = wvp[2], w3 = wvp[3];
        float sd = v0.x*w0.x + v0.y*w0.y + v0.z*w0.z + v0.w*w0.w
                 + v1.x*w1.x + v1.y*w1.y + v1.z*w1.z + v1.w*w1.w
                 + v2.x*w2.x + v2.y*w2.y + v2.z*w2.z + v2.w*w2.w
                 + v3.x*w3.x + v3.y*w3.y + v3.z*w3.z + v3.w*w3.w;
        int cb = cq * 32;
        *(uint4*)(sm + R0 + r*256 + (cb ^ s)) =
            make_uint4(pkbf(v0.x,v0.y), pkbf(v0.z,v0.w), pkbf(v1.x,v1.y), pkbf(v1.z,v1.w));
        *(uint4*)(sm + R0 + r*256 + ((cb + 16) ^ s)) =
            make_uint4(pkbf(v2.x,v2.y), pkbf(v2.z,v2.w), pkbf(v3.x,v3.y), pkbf(v3.z,v3.w));
        sd += __shfl_xor(sd, 1); sd += __shfl_xor(sd, 2); sd += __shfl_xor(sd, 4);
        if (cq == 0) {
            int sn = p.ei[eid];
            int dn = p.ei[E_EDGES + eid];
            float a = sd + p.p1[sn] + p.p2[dn];
            float ex = __expf(a);                 // max-free: att bounded ~|6|
            ((float*)(sm + AL_S))[r] = ex;
            unsafeAtomicAdd(&p.den[sn], ex);
        }
    }
    // e-chain (ea in R0 live through m0)
    do_gemm<128,128,3,4>(sm, p, R0, 0,  wtE0, R1, 0,  nullptr, wtE1, bbuf, wr, wc, lane);
    do_gemm<128,128,1,4>(sm, p, R1, 0,  wtE1, R2, 0,  p.eb1,   wtE2, bbuf, wr, wc, lane);
    do_gemm<128,128,4,4>(sm, p, R2, 0,  wtE2, 0,  0,  nullptr, wtM0, bbuf, wr, wc, lane);
    // m-chain: h0m -> (R1,R2), h1m -> (R0,R3), m2 dumps fp32 to R0..R3
    do_gemm<128,256,0,4>(sm, p, R0, 0,  wtM0, R1, R2, nullptr, wtM1, bbuf, wr, wc, lane);
    do_gemm<256,256,1,4>(sm, p, R1, R2, wtM1, R0, R3, p.mb1,   wtM2, bbuf, wr, wc, lane);
    do_gemm<256,256,2,0>(sm, p, R0, R3, wtM2, 0,  0,  nullptr, nullptr, bbuf, wr, wc, lane);
    bar_ldsonly();
    // segmented reduction over sorted src: one atomic per (segment, col)
    {
        const int* srcid = (const int*)(sm + SRC_S);
        int h = tid >> 8;
        int c = tid & 255;
        int rend = h * 32 + 31;
        float acc = 0.f;
        for (int r = h * 32; r <= rend; r++) {
            acc += *(const float*)(sm + dump_addr(r, c));
            if (r == rend || srcid[r + 1] != srcid[r]) {
                unsafeAtomicAdd(&p.xa[(size_t)srcid[r] * ND + c], acc);
                acc = 0.f;
            }
        }
    }
}

// ---------------- normalize ----------------
__global__ void k_norm(const float* xa, const float* den, float* xout) {
    int i = blockIdx.x * 256 + threadIdx.x;
    if (i >= N_NODES * ND) return;
    float d = den[i >> 8];
    xout[i] = (d > 0.f) ? xa[i] / d : 0.f;
}

extern "C" void kernel_launch(void* const* d_in, const int* in_sizes, int n_in,
                              void* d_out, int out_size, void* d_ws, size_t ws_size,
                              hipStream_t stream) {
    const float* na  = (const float*)d_in[0];
    const float* ea  = (const float*)d_in[1];
    const int*   ei  = (const int*)d_in[2];
    const float* mw0 = (const float*)d_in[3];
    const float* mb0 = (const float*)d_in[4];
    const float* mw1 = (const float*)d_in[5];
    const float* mb1 = (const float*)d_in[6];
    const float* mw2 = (const float*)d_in[7];
    const float* mb2 = (const float*)d_in[8];
    const float* ew0 = (const float*)d_in[9];
    const float* eb0 = (const float*)d_in[10];
    const float* ew1 = (const float*)d_in[11];
    const float* eb1 = (const float*)d_in[12];
    const float* ew2 = (const float*)d_in[13];
    const float* eb2 = (const float*)d_in[14];
    const float* aw  = (const float*)d_in[15];
    const float* ab  = (const float*)d_in[16];
    float* out = (float*)d_out;
    char*  wsb = (char*)d_ws;

    float* xout = out;
    float* eout = out + (size_t)N_NODES * ND;

    float* xa  = (float*)(wsb + B_XA);
    float* den = (float*)(wsb + B_DEN);
    int*   cnt = (int*)(wsb + B_CNT);
    int*   row = (int*)(wsb + B_ROW);
    int*   cur = (int*)(wsb + B_CUR);
    int*   eidcsr = (int*)(wsb + B_EID);

    k_init<<<512, 256, 0, stream>>>(xa, den, cnt, cur);
    k_deg<<<1250, 256, 0, stream>>>(ei, cnt);
    k_scan<<<1, 1024, 0, stream>>>(cnt, row);
    k_fill<<<1250, 256, 0, stream>>>(ei, row, cur, eidcsr);
    k_wconv<<<256, 256, 0, stream>>>(mw0, mw1, mw2, ew0, ew1, ew2, wsb + B_WT);
    k_nodepre<<<dim3(1250, 4), 256, 0, stream>>>(na, mw0, ew0, aw, mb0, eb0, ab, wsb);

    DP p{ea, ei, eidcsr,
         (const unsigned short*)(wsb + B_AM), (const unsigned short*)(wsb + B_BM),
         (const unsigned short*)(wsb + B_AE), (const unsigned short*)(wsb + B_BE),
         (const float*)(wsb + B_P1), (const float*)(wsb + B_P2), aw,
         mb1, mb2, eb1, eb2, (const char*)(wsb + B_WT), xa, den, eout};
    hipFuncSetAttribute((const void*)k_main, hipFuncAttributeMaxDynamicSharedMemorySize, LDS_TOT);
    k_main<<<NTILES, 512, LDS_TOT, stream>>>(p);
    k_norm<<<10000, 256, 0, stream>>>(xa, den, xout);
}

// Round 14
// 443.797 us; speedup vs baseline: 1.8548x; 1.1345x over previous
//
#include <hip/hip_runtime.h>
#include <hip/hip_bf16.h>

#define N_NODES 10000
#define E_EDGES 320000
#define ND 256
#define ED 128

// ---- workspace layout (BYTE offsets); total ~27.9 MB ----
#define B_AM   0          // bf16 [10000][256]
#define B_BM   5120000    // bf16 [10000][256]
#define B_AE   10240000   // bf16 [10000][128]
#define B_BE   12800000   // bf16 [10000][128]
#define B_P1   15360000   // f32 [10000]
#define B_P2   15400960   // f32 [10000]
#define B_XA   15441920   // f32 [10000][256] accumulator
#define B_DEN  25681920   // f32 [10000]
#define B_CNT  25722880   // int [10000]
#define B_ROW  25763840   // int [10000]
#define B_CUR  25804800   // int [10000]
#define B_EID  25845760   // int [320000] CSR edge ids
#define B_WT   27125760   // bf16 weight tables, 819200 bytes

// main-kernel weight tables, PACKED per 4 col-groups in wave-read order:
// [wc(4)][kk(NK)][cf(CF)][lane(64)][j(8)] bf16 -> 1KB coalesced blocks
#define M0T 0
#define M1T 65536
#define M2T 196608
#define E0T 327680
#define E1T 360448
#define E2T 393216
// node-precompute weight sections (6 x 128 cols x 256 k), same packing, CF=2 NK=8:
// sec 0/1: Am lo/hi (mw0 rows 0:256) 2/3: Bm lo/hi (mw0 rows 256:512) 4: Ae 5: Be
#define NPT0 425984
#define NPSEC 65536

// ---- LDS: four 16KB panels [64 rows][256B] + control ----
#define R0 0
#define R1 16384
#define R2 32768
#define R3 49152
#define AL_S  65536
#define SRC_S 65792
#define DST_S 66048
#define EID_S 66304
#define LDS_TOT 66560

#define BM 64
#define NTILES (E_EDGES / BM)

typedef float  float4v __attribute__((ext_vector_type(4)));
typedef short  short8  __attribute__((ext_vector_type(8)));

__device__ __forceinline__ unsigned short f2bf(float f) {
    unsigned int b = __float_as_uint(f);
    return (unsigned short)((b + 0x7FFFu + ((b >> 16) & 1u)) >> 16);
}
__device__ __forceinline__ float bf2f(unsigned short u) {
    return __uint_as_float(((unsigned int)u) << 16);
}
// HW-packed bf16 pair (v_cvt_pk_bf16_f32, RNE — bit-identical to f2bf pair).
__device__ __forceinline__ unsigned int pkbf(float a, float b) {
    __hip_bfloat162 h = __float22bfloat162_rn(float2{a, b});
    return *(unsigned int*)&h;
}

// Non-draining barrier (T4): waits LDS ops only, then raw s_barrier.
__device__ __forceinline__ void bar_ldsonly() {
    asm volatile("s_waitcnt lgkmcnt(0)" ::: "memory");
    __builtin_amdgcn_s_barrier();
}

// ---------------- init ----------------
__global__ void k_init(float* xa, float* den, int* cnt, int* cur) {
    int i = blockIdx.x * blockDim.x + threadIdx.x;
    int st = gridDim.x * blockDim.x;
    for (int j = i; j < N_NODES * ND; j += st) xa[j] = 0.f;
    for (int j = i; j < N_NODES; j += st) { den[j] = 0.f; cnt[j] = 0; cur[j] = 0; }
}

// ---------------- CSR build ----------------
__global__ void k_deg(const int* ei, int* cnt) {
    int e = blockIdx.x * 256 + threadIdx.x;
    if (e < E_EDGES) atomicAdd(&cnt[ei[e]], 1);
}

__global__ __launch_bounds__(1024) void k_scan(const int* cnt, int* rowstart) {
    __shared__ int wsum[16];
    int t = threadIdx.x, lane = t & 63, w = t >> 6;
    int base = t * 10;
    int loc[10];
    int s = 0;
    #pragma unroll
    for (int i = 0; i < 10; i++) {
        int idx = base + i;
        int v = (idx < N_NODES) ? cnt[idx] : 0;
        loc[i] = s; s += v;
    }
    int run = s;
    #pragma unroll
    for (int d = 1; d < 64; d <<= 1) {
        int u = __shfl_up(run, d);
        if (lane >= d) run += u;
    }
    if (lane == 63) wsum[w] = run;
    __syncthreads();
    if (w == 0 && lane < 16) {
        int v = wsum[lane];
        int r = v;
        #pragma unroll
        for (int d = 1; d < 16; d <<= 1) {
            int u = __shfl_up(r, d);
            if (lane >= d) r += u;
        }
        wsum[lane] = r - v;
    }
    __syncthreads();
    int ex = wsum[w] + run - s;
    #pragma unroll
    for (int i = 0; i < 10; i++) {
        int idx = base + i;
        if (idx < N_NODES) rowstart[idx] = ex + loc[i];
    }
}

__global__ void k_fill(const int* ei, const int* rowstart, int* cur, int* eidcsr) {
    int e = blockIdx.x * 256 + threadIdx.x;
    if (e >= E_EDGES) return;
    int s = ei[e];
    int p = atomicAdd(&cur[s], 1);
    eidcsr[rowstart[s] + p] = e;
}

// ---------------- weight convert: main tables + node-precompute sections ----------------
__global__ void k_wconv(const float* mw0, const float* mw1, const float* mw2,
                        const float* ew0, const float* ew1, const float* ew2, char* wtb) {
    const int tot = 409600;   // 212992 main + 196608 np
    for (int idx = blockIdx.x * blockDim.x + threadIdx.x; idx < tot;
         idx += gridDim.x * blockDim.x) {
        if (idx < 212992) {
            int local, K, N, base; const float* src;
            if (idx < 32768)       { local = idx;          K = 128; N = 256; src = mw0 + 512*256; base = M0T; }
            else if (idx < 98304)  { local = idx - 32768;  K = 256; N = 256; src = mw1;           base = M1T; }
            else if (idx < 163840) { local = idx - 98304;  K = 256; N = 256; src = mw2;           base = M2T; }
            else if (idx < 180224) { local = idx - 163840; K = 128; N = 128; src = ew0 + 512*128; base = E0T; }
            else if (idx < 196608) { local = idx - 180224; K = 128; N = 128; src = ew1;           base = E1T; }
            else                   { local = idx - 196608; K = 128; N = 128; src = ew2;           base = E2T; }
            int W4 = N / 4;
            int CF = W4 >> 4;
            int NK = K / 32;
            int t = local;
            int j    = t & 7;   t >>= 3;
            int lane = t & 63;  t >>= 6;
            int cf   = t % CF;  t /= CF;
            int kk   = t % NK;  t /= NK;
            int wc   = t;
            int col = wc * W4 + cf * 16 + (lane & 15);
            int k   = kk * 32 + (lane >> 4) * 8 + j;
            ((unsigned short*)(wtb + base))[local] = f2bf(src[k * N + col]);
        } else {
            int q = idx - 212992;            // 0..196607
            int sec = q >> 15;               // /32768
            int local = q & 32767;
            int t = local;                   // CF=2, NK=8 decomposition
            int j    = t & 7;   t >>= 3;
            int lane = t & 63;  t >>= 6;
            int cf   = t & 1;   t >>= 1;
            int kk   = t & 7;   t >>= 3;
            int wc   = t;                    // 0..3
            int col = wc * 32 + cf * 16 + (lane & 15);
            int k   = kk * 32 + (lane >> 4) * 8 + j;
            const float* src; int N;
            if (sec == 0)      { src = mw0;         N = 256; }
            else if (sec == 1) { src = mw0;         N = 256; col += 128; }
            else if (sec == 2) { src = mw0 + 65536; N = 256; }
            else if (sec == 3) { src = mw0 + 65536; N = 256; col += 128; }
            else if (sec == 4) { src = ew0;         N = 128; }
            else               { src = ew0 + 32768; N = 128; }
            ((unsigned short*)(wtb + NPT0 + sec * NPSEC))[local] = f2bf(src[k * N + col]);
        }
    }
}

// ---------------- node tables via MFMA: [10000,256]@[256,128] per section ----------------
__device__ __forceinline__ int np_addr(int row, int keb) {   // keb = byte k-offset
    return row * 512 + (keb ^ ((row & 7) << 4));
}

__global__ __launch_bounds__(512, 2) void k_npgemm(const float* na, const float* mb0,
                                                   const float* eb0, char* wsb) {
    __shared__ char sm[32768];     // [64 rows][512B] bf16, XOR-swizzled
    const int tid = threadIdx.x;
    const int lane = tid & 63, wv = tid >> 6;
    const int wr = wv >> 2, wc = wv & 3;
    const int l15 = lane & 15, lg = lane >> 4;
    const int n0 = blockIdx.x * 64;
    const int sec = blockIdx.y;

    const char* wt = wsb + B_WT + NPT0 + (size_t)sec * NPSEC + (size_t)wc * 16384;
    short8 bbuf[2][4];
    #pragma unroll
    for (int i = 0; i < 4; i++)
        bbuf[0][i] = *(const short8*)(wt + ((size_t)i * 64 + lane) * 16);

    // stage na[64][256] f32 -> bf16 swizzled (zero-pad past N_NODES)
    {
        int r = tid >> 3, cq = tid & 7;
        int node = n0 + r;
        int sxor = (r & 7) << 4;
        if (node < N_NODES) {
            const float4* src = (const float4*)(na + (size_t)node * ND + cq * 32);
            #pragma unroll
            for (int g = 0; g < 4; g++) {
                float4 va = src[g*2], vb = src[g*2+1];
                uint4 pk = make_uint4(pkbf(va.x,va.y), pkbf(va.z,va.w),
                                      pkbf(vb.x,vb.y), pkbf(vb.z,vb.w));
                *(uint4*)(sm + np_addr(r, (cq*32 + g*8)*2)) = pk;
            }
        } else {
            #pragma unroll
            for (int g = 0; g < 4; g++)
                *(uint4*)(sm + np_addr(r, (cq*32 + g*8)*2)) = make_uint4(0,0,0,0);
        }
    }
    bar_ldsonly();

    const float4v vz = {0.f, 0.f, 0.f, 0.f};
    float4v acc[2][2];
    #pragma unroll
    for (int i = 0; i < 2; i++) { acc[i][0] = vz; acc[i][1] = vz; }

    short8 areg[2][2];
    #pragma unroll
    for (int rf = 0; rf < 2; rf++)
        areg[0][rf] = *(const short8*)(sm + np_addr(wr*32 + rf*16 + l15, lg*16));

    #pragma unroll
    for (int h = 0; h < 4; h++) {          // KH=4 chunks of 4 blocks (2 ksteps)
        if (h + 1 < 4) {
            #pragma unroll
            for (int i = 0; i < 4; i++)
                bbuf[(h+1)&1][i] = *(const short8*)(wt + ((size_t)((h+1)*4 + i) * 64 + lane) * 16);
        }
        #pragma unroll
        for (int ks = 0; ks < 2; ks++) {
            int kstep = h * 2 + ks;
            if (kstep + 1 < 8) {
                int keb = (kstep + 1) * 64 + lg * 16;
                #pragma unroll
                for (int rf = 0; rf < 2; rf++)
                    areg[(kstep+1)&1][rf] = *(const short8*)(sm + np_addr(wr*32 + rf*16 + l15, keb));
            }
            #pragma unroll
            for (int rf = 0; rf < 2; rf++)
                #pragma unroll
                for (int cf = 0; cf < 2; cf++)
                    acc[rf][cf] = __builtin_amdgcn_mfma_f32_16x16x32_bf16(areg[kstep&1][rf], bbuf[h&1][ks*2+cf], acc[rf][cf], 0, 0, 0);
        }
    }
    // epilogue: bias + bf16 -> table
    const float* bias = nullptr;
    unsigned short* outp; int ostride; int coladd = 0;
    if (sec == 0)      { outp = (unsigned short*)(wsb + B_AM); ostride = 256; bias = mb0; }
    else if (sec == 1) { outp = (unsigned short*)(wsb + B_AM); ostride = 256; bias = mb0 + 128; coladd = 128; }
    else if (sec == 2) { outp = (unsigned short*)(wsb + B_BM); ostride = 256; }
    else if (sec == 3) { outp = (unsigned short*)(wsb + B_BM); ostride = 256; coladd = 128; }
    else if (sec == 4) { outp = (unsigned short*)(wsb + B_AE); ostride = 128; bias = eb0; }
    else               { outp = (unsigned short*)(wsb + B_BE); ostride = 128; }
    #pragma unroll
    for (int rf = 0; rf < 2; rf++)
        #pragma unroll
        for (int cf = 0; cf < 2; cf++) {
            int colLoc = wc * 32 + cf * 16 + l15;
            float b = bias ? bias[colLoc] : 0.f;
            #pragma unroll
            for (int j = 0; j < 4; j++) {
                int node = n0 + wr*32 + rf*16 + lg*4 + j;
                if (node < N_NODES)
                    outp[(size_t)node * ostride + coladd + colLoc] = f2bf(acc[rf][cf][j] + b);
            }
        }
}

// ---------------- attention projections p1/p2 (fp32 exact) ----------------
__global__ __launch_bounds__(256) void k_p1p2(const float* na, const float* aw,
                                              const float* ab, char* wsb) {
    int t = blockIdx.x * 256 + threadIdx.x;
    int node = t >> 4, kc = t & 15;          // 16 lanes per node, coalesced
    if (node >= N_NODES) return;
    const float4* row = (const float4*)(na + (size_t)node * ND + kc * 16);
    const float4* w1p = (const float4*)(aw + kc * 16);
    const float4* w2p = (const float4*)(aw + 256 + kc * 16);
    float s1 = 0.f, s2 = 0.f;
    #pragma unroll
    for (int i = 0; i < 4; i++) {
        float4 v = row[i], w1 = w1p[i], w2 = w2p[i];
        s1 += v.x*w1.x + v.y*w1.y + v.z*w1.z + v.w*w1.w;
        s2 += v.x*w2.x + v.y*w2.y + v.z*w2.z + v.w*w2.w;
    }
    s1 += __shfl_xor(s1, 1); s1 += __shfl_xor(s1, 2);
    s1 += __shfl_xor(s1, 4); s1 += __shfl_xor(s1, 8);
    s2 += __shfl_xor(s2, 1); s2 += __shfl_xor(s2, 2);
    s2 += __shfl_xor(s2, 4); s2 += __shfl_xor(s2, 8);
    if (kc == 0) {
        ((float*)(wsb + B_P1))[node] = s1 + ab[0];
        ((float*)(wsb + B_P2))[node] = s2;
    }
}

// ---------------- fused per-edge MLP main kernel (UNCHANGED from r13) ----------------
struct DP {
    const float* ea; const int* ei; const int* csr;
    const unsigned short* Am; const unsigned short* Bm;
    const unsigned short* Ae; const unsigned short* Be;
    const float* p1; const float* p2; const float* aw;
    const float* mb1; const float* mb2; const float* eb1; const float* eb2;
    const char* wtb;
    float* xa; float* den; float* eout;
};

__device__ __forceinline__ int pan_addr(int blo, int bhi, int row, int col) {
    int base = (col & 128) ? bhi : blo;
    return base + row * 256 + ((((col & 127)) * 2) ^ ((row & 7) << 4));
}
__device__ __forceinline__ int dump_addr(int row, int col) {
    return row * 1024 + (((col * 4)) ^ ((row & 15) << 6));
}

template<int KTOT, int NOUT, int EPI, int NXT_N>
__device__ __forceinline__ void do_gemm(char* sm, const DP& p,
                                        int a_lo, int a_hi, const char* wt,
                                        int h_lo, int h_hi, const float* bias,
                                        const char* wt_next, short8 (&bbuf)[2][4],
                                        int wr, int wc, int lane) {
    constexpr int WCOL = NOUT / 4;
    constexpr int CF   = WCOL / 16;
    constexpr int NK   = KTOT / 32;
    constexpr int KH   = NK * CF / 4;
    constexpr int NKH  = NK / KH;
    const int l15 = lane & 15, lg = lane >> 4;
    const float4v vz = {0.f, 0.f, 0.f, 0.f};
    float4v acc[2][CF];
    #pragma unroll
    for (int i = 0; i < 2; i++)
        #pragma unroll
        for (int j = 0; j < CF; j++) acc[i][j] = vz;
    bar_ldsonly();
    short8 areg[2][2];
    #pragma unroll
    for (int rf = 0; rf < 2; rf++)
        areg[0][rf] = *(const short8*)(sm + pan_addr(a_lo, a_hi, wr*32 + rf*16 + l15, lg*8));
    #pragma unroll
    for (int h = 0; h < KH; h++) {
        if (h + 1 < KH) {
            #pragma unroll
            for (int i = 0; i < 4; i++)
                bbuf[(h+1)&1][i] = *(const short8*)(wt + ((size_t)((h+1)*4 + i) * 64 + lane) * 16);
        } else if constexpr (NXT_N > 0) {
            #pragma unroll
            for (int i = 0; i < NXT_N; i++)
                bbuf[(h+1)&1][i] = *(const short8*)(wt_next + ((size_t)i * 64 + lane) * 16);
        }
        #pragma unroll
        for (int ks = 0; ks < NKH; ks++) {
            int kstep = h * NKH + ks;
            if (kstep + 1 < NK) {
                int ke = (kstep + 1) * 32 + lg * 8;
                #pragma unroll
                for (int rf = 0; rf < 2; rf++)
                    areg[(kstep+1)&1][rf] = *(const short8*)(sm + pan_addr(a_lo, a_hi, wr*32 + rf*16 + l15, ke));
            }
            #pragma unroll
            for (int rf = 0; rf < 2; rf++)
                #pragma unroll
                for (int cf = 0; cf < CF; cf++)
                    acc[rf][cf] = __builtin_amdgcn_mfma_f32_16x16x32_bf16(areg[kstep&1][rf], bbuf[h&1][ks*CF+cf], acc[rf][cf], 0, 0, 0);
        }
    }
    if constexpr (EPI == 2) bar_ldsonly();
    const int*   srcid = (const int*)(sm + SRC_S);
    const int*   dstid = (const int*)(sm + DST_S);
    const int*   eid   = (const int*)(sm + EID_S);
    const float* exv   = (const float*)(sm + AL_S);
    #pragma unroll
    for (int rf = 0; rf < 2; rf++)
        #pragma unroll
        for (int cf = 0; cf < CF; cf++) {
            int col = wc * WCOL + cf * 16 + l15;
            int row0 = wr * 32 + rf * 16 + lg * 4;
            if constexpr (EPI == 0 || EPI == 1 || EPI == 3) {
                float vv[4];
                #pragma unroll
                for (int j = 0; j < 4; j++) {
                    int row = row0 + j;
                    float v = acc[rf][cf][j];
                    if constexpr (EPI == 0)
                        v += bf2f(p.Am[(size_t)srcid[row] * ND + col]) + bf2f(p.Bm[(size_t)dstid[row] * ND + col]);
                    else if constexpr (EPI == 1)
                        v += bias[col];
                    else
                        v += bf2f(p.Ae[(size_t)srcid[row] * ED + col]) + bf2f(p.Be[(size_t)dstid[row] * ED + col]);
                    vv[j] = fmaxf(v, 0.f);
                }
                unsigned w01 = pkbf(vv[0], vv[1]);
                unsigned w23 = pkbf(vv[2], vv[3]);
                *(unsigned short*)(sm + pan_addr(h_lo, h_hi, row0 + 0, col)) = (unsigned short)w01;
                *(unsigned short*)(sm + pan_addr(h_lo, h_hi, row0 + 1, col)) = (unsigned short)(w01 >> 16);
                *(unsigned short*)(sm + pan_addr(h_lo, h_hi, row0 + 2, col)) = (unsigned short)w23;
                *(unsigned short*)(sm + pan_addr(h_lo, h_hi, row0 + 3, col)) = (unsigned short)(w23 >> 16);
            } else {
                #pragma unroll
                for (int j = 0; j < 4; j++) {
                    int row = row0 + j;
                    float v = acc[rf][cf][j];
                    if constexpr (EPI == 2) {
                        v = (v + p.mb2[col]) * exv[row];
                        *(float*)(sm + dump_addr(row, col)) = v;
                    } else {
                        v += p.eb2[col];
                        p.eout[(size_t)eid[row] * ED + col] = v;
                    }
                }
            }
        }
}

__global__ __launch_bounds__(512, 4) void k_main(DP p) {
    extern __shared__ char sm[];
    const int tid = threadIdx.x;
    const int lane = tid & 63, wv = tid >> 6;
    const int wr = wv >> 2, wc = wv & 3;
    const int s0 = blockIdx.x * BM;

    const char* wtE0 = p.wtb + E0T + (size_t)wc * 8192;
    const char* wtE1 = p.wtb + E1T + (size_t)wc * 8192;
    const char* wtE2 = p.wtb + E2T + (size_t)wc * 8192;
    const char* wtM0 = p.wtb + M0T + (size_t)wc * 16384;
    const char* wtM1 = p.wtb + M1T + (size_t)wc * 32768;
    const char* wtM2 = p.wtb + M2T + (size_t)wc * 32768;

    short8 bbuf[2][4];
    #pragma unroll
    for (int i = 0; i < 4; i++)
        bbuf[0][i] = *(const short8*)(wtE0 + ((size_t)i * 64 + lane) * 16);

    if (tid < BM) {
        int eid = p.csr[s0 + tid];
        ((int*)(sm + EID_S))[tid] = eid;
        ((int*)(sm + SRC_S))[tid] = p.ei[eid];
        ((int*)(sm + DST_S))[tid] = p.ei[E_EDGES + eid];
    }
    {
        int r = tid >> 3, cq = tid & 7;
        int eid = p.csr[s0 + r];
        const float4* src = (const float4*)(p.ea + (size_t)eid * ED + cq * 16);
        const float4* wvp = (const float4*)(p.aw + 512 + cq * 16);
        int s = (r & 7) << 4;
        float4 v0 = src[0], v1 = src[1], v2 = src[2], v3 = src[3];
        float4 w0 = wvp[0], w1 = wvp[1], w2 = wvp[2], w3 = wvp[3];
        float sd = v0.x*w0.x + v0.y*w0.y + v0.z*w0.z + v0.w*w0.w
                 + v1.x*w1.x + v1.y*w1.y + v1.z*w1.z + v1.w*w1.w
                 + v2.x*w2.x + v2.y*w2.y + v2.z*w2.z + v2.w*w2.w
                 + v3.x*w3.x + v3.y*w3.y + v3.z*w3.z + v3.w*w3.w;
        int cb = cq * 32;
        *(uint4*)(sm + R0 + r*256 + (cb ^ s)) =
            make_uint4(pkbf(v0.x,v0.y), pkbf(v0.z,v0.w), pkbf(v1.x,v1.y), pkbf(v1.z,v1.w));
        *(uint4*)(sm + R0 + r*256 + ((cb + 16) ^ s)) =
            make_uint4(pkbf(v2.x,v2.y), pkbf(v2.z,v2.w), pkbf(v3.x,v3.y), pkbf(v3.z,v3.w));
        sd += __shfl_xor(sd, 1); sd += __shfl_xor(sd, 2); sd += __shfl_xor(sd, 4);
        if (cq == 0) {
            int sn = p.ei[eid];
            int dn = p.ei[E_EDGES + eid];
            float a = sd + p.p1[sn] + p.p2[dn];
            float ex = __expf(a);
            ((float*)(sm + AL_S))[r] = ex;
            unsafeAtomicAdd(&p.den[sn], ex);
        }
    }
    do_gemm<128,128,3,4>(sm, p, R0, 0,  wtE0, R1, 0,  nullptr, wtE1, bbuf, wr, wc, lane);
    do_gemm<128,128,1,4>(sm, p, R1, 0,  wtE1, R2, 0,  p.eb1,   wtE2, bbuf, wr, wc, lane);
    do_gemm<128,128,4,4>(sm, p, R2, 0,  wtE2, 0,  0,  nullptr, wtM0, bbuf, wr, wc, lane);
    do_gemm<128,256,0,4>(sm, p, R0, 0,  wtM0, R1, R2, nullptr, wtM1, bbuf, wr, wc, lane);
    do_gemm<256,256,1,4>(sm, p, R1, R2, wtM1, R0, R3, p.mb1,   wtM2, bbuf, wr, wc, lane);
    do_gemm<256,256,2,0>(sm, p, R0, R3, wtM2, 0,  0,  nullptr, nullptr, bbuf, wr, wc, lane);
    bar_ldsonly();
    {
        const int* srcid = (const int*)(sm + SRC_S);
        int h = tid >> 8;
        int c = tid & 255;
        int rend = h * 32 + 31;
        float acc = 0.f;
        for (int r = h * 32; r <= rend; r++) {
            acc += *(const float*)(sm + dump_addr(r, c));
            if (r == rend || srcid[r + 1] != srcid[r]) {
                unsafeAtomicAdd(&p.xa[(size_t)srcid[r] * ND + c], acc);
                acc = 0.f;
            }
        }
    }
}

// ---------------- normalize ----------------
__global__ void k_norm(const float* xa, const float* den, float* xout) {
    int i = blockIdx.x * 256 + threadIdx.x;
    if (i >= N_NODES * ND) return;
    float d = den[i >> 8];
    xout[i] = (d > 0.f) ? xa[i] / d : 0.f;
}

extern "C" void kernel_launch(void* const* d_in, const int* in_sizes, int n_in,
                              void* d_out, int out_size, void* d_ws, size_t ws_size,
                              hipStream_t stream) {
    const float* na  = (const float*)d_in[0];
    const float* ea  = (const float*)d_in[1];
    const int*   ei  = (const int*)d_in[2];
    const float* mw0 = (const float*)d_in[3];
    const float* mb0 = (const float*)d_in[4];
    const float* mw1 = (const float*)d_in[5];
    const float* mb1 = (const float*)d_in[6];
    const float* mw2 = (const float*)d_in[7];
    const float* mb2 = (const float*)d_in[8];
    const float* ew0 = (const float*)d_in[9];
    const float* eb0 = (const float*)d_in[10];
    const float* ew1 = (const float*)d_in[11];
    const float* eb1 = (const float*)d_in[12];
    const float* ew2 = (const float*)d_in[13];
    const float* eb2 = (const float*)d_in[14];
    const float* aw  = (const float*)d_in[15];
    const float* ab  = (const float*)d_in[16];
    float* out = (float*)d_out;
    char*  wsb = (char*)d_ws;

    float* xout = out;
    float* eout = out + (size_t)N_NODES * ND;

    float* xa  = (float*)(wsb + B_XA);
    float* den = (float*)(wsb + B_DEN);
    int*   cnt = (int*)(wsb + B_CNT);
    int*   row = (int*)(wsb + B_ROW);
    int*   cur = (int*)(wsb + B_CUR);
    int*   eidcsr = (int*)(wsb + B_EID);

    k_init<<<512, 256, 0, stream>>>(xa, den, cnt, cur);
    k_deg<<<1250, 256, 0, stream>>>(ei, cnt);
    k_scan<<<1, 1024, 0, stream>>>(cnt, row);
    k_fill<<<1250, 256, 0, stream>>>(ei, row, cur, eidcsr);
    k_wconv<<<400, 256, 0, stream>>>(mw0, mw1, mw2, ew0, ew1, ew2, wsb + B_WT);
    k_npgemm<<<dim3(157, 6), 512, 0, stream>>>(na, mb0, eb0, wsb);
    k_p1p2<<<625, 256, 0, stream>>>(na, aw, ab, wsb);

    DP p{ea, ei, eidcsr,
         (const unsigned short*)(wsb + B_AM), (const unsigned short*)(wsb + B_BM),
         (const unsigned short*)(wsb + B_AE), (const unsigned short*)(wsb + B_BE),
         (const float*)(wsb + B_P1), (const float*)(wsb + B_P2), aw,
         mb1, mb2, eb1, eb2, (const char*)(wsb + B_WT), xa, den, eout};
    hipFuncSetAttribute((const void*)k_main, hipFuncAttributeMaxDynamicSharedMemorySize, LDS_TOT);
    k_main<<<NTILES, 512, LDS_TOT, stream>>>(p);
    k_norm<<<10000, 256, 0, stream>>>(xa, den, xout);
}